// Round 7
// baseline (366.202 us; speedup 1.0000x reference)
//
#include <hip/hip_runtime.h>
#include <hip/hip_bf16.h>
#include <stdint.h>

#define S_LEN 2048
#define HDIM  2048
#define NHQ   16
#define NKVH  4
#define HD    128
#define WIN   1024
#define QKV_N 3072          // 2048 q | 512 k | 512 v
#define SM_SCALE 0.08838834764831845f
#define NEG_BIG  -1.0e30f

typedef __attribute__((ext_vector_type(8))) short short8;
typedef __attribute__((ext_vector_type(4))) float float4v;
typedef unsigned short u16;

static __device__ __forceinline__ float bf2f(u16 u) {
  union { unsigned int i; float f; } v; v.i = ((unsigned int)u) << 16; return v.f;
}
static __device__ __forceinline__ u16 f2bf(float f) {
  union { float f; unsigned int i; } v; v.f = f;
  unsigned int x = v.i;
  return (u16)((x + 0x7fffu + ((x >> 16) & 1u)) >> 16);   // RNE, finite inputs
}

// ---------------------------------------------------------------------------
// fp32 -> bf16 elementwise convert (hidden_state). n divisible by 1024.
// ---------------------------------------------------------------------------
__global__ __launch_bounds__(256) void cvt_f32_bf16(
    const float* __restrict__ x, u16* __restrict__ y, int n)
{
  const int i = (blockIdx.x * 256 + threadIdx.x) * 4;
  if (i < n) {
    const float4 v = *(const float4*)(x + i);
    y[i + 0] = f2bf(v.x);
    y[i + 1] = f2bf(v.y);
    y[i + 2] = f2bf(v.z);
    y[i + 3] = f2bf(v.w);
  }
}

// ---------------------------------------------------------------------------
// Fused convert+transpose: W fp32 [K][N] -> WT bf16 [N][K].
// ---------------------------------------------------------------------------
__global__ __launch_bounds__(256) void transpose_f32_bf16(
    const float* __restrict__ W, u16* __restrict__ WT, int K, int N)
{
  __shared__ u16 t[32][33];
  const int n0 = blockIdx.x * 32, k0 = blockIdx.y * 32;
  const int tx = threadIdx.x & 31, ty = threadIdx.x >> 5;
#pragma unroll
  for (int i = 0; i < 4; ++i)
    t[ty + i * 8][tx] = f2bf(W[(size_t)(k0 + ty + i * 8) * N + n0 + tx]);
  __syncthreads();
#pragma unroll
  for (int i = 0; i < 4; ++i)
    WT[(size_t)(n0 + ty + i * 8) * K + k0 + tx] = t[tx][ty + i * 8];
}

// ---------------------------------------------------------------------------
// V transpose: QKV v-section [s][2560 + kvh*128 + hd] -> VT[kvh][hd][s].
// ---------------------------------------------------------------------------
__global__ __launch_bounds__(256) void v_transpose(
    const u16* __restrict__ qkv, u16* __restrict__ vt)
{
  __shared__ u16 t[32][33];
  const int s0  = blockIdx.x * 32;
  const int h0  = blockIdx.y * 32;
  const int kvh = blockIdx.z;
  const int tx = threadIdx.x & 31, ty = threadIdx.x >> 5;
#pragma unroll
  for (int i = 0; i < 4; ++i)
    t[ty + i * 8][tx] = qkv[(size_t)(s0 + ty + i * 8) * QKV_N + 2560 + kvh * HD + h0 + tx];
  __syncthreads();
#pragma unroll
  for (int i = 0; i < 4; ++i)
    vt[(size_t)(kvh * HD + h0 + ty + i * 8) * S_LEN + s0 + tx] = t[tx][ty + i * 8];
}

// ---------------------------------------------------------------------------
// GEMM: C = A[M,K] * BT[N,K]^T, bf16 in, fp32 accum. m97 template.
// ---------------------------------------------------------------------------
template <bool OUT_F32>
__global__ __launch_bounds__(256) void gemm_bt(
    const u16* __restrict__ A, const u16* __restrict__ BT,
    void* __restrict__ Cv, int M, int N, int K)
{
  __shared__ u16 Als[128 * 32];
  __shared__ u16 Bls[128 * 32];

  const int tid  = threadIdx.x;
  const int lane = tid & 63;
  const int w    = tid >> 6;
  const int quad = lane >> 4;
  const int lc   = lane & 15;
  const int n0   = blockIdx.x * 128;
  const int m0   = blockIdx.y * 128;
  const int wr   = (w >> 1) * 64;
  const int wc   = (w & 1) * 64;

  float4v acc[4][4];
#pragma unroll
  for (int i = 0; i < 4; ++i)
#pragma unroll
    for (int j = 0; j < 4; ++j) acc[i][j] = (float4v){0.f, 0.f, 0.f, 0.f};

  const int offBase = w * 1024 + lane * 16;

  for (int k0 = 0; k0 < K; k0 += 32) {
    __syncthreads();
#pragma unroll
    for (int r = 0; r < 2; ++r) {
      const int off  = r * 4096 + offBase;
      const int row  = off >> 6;
      const int colb = off & 63;
      const u16* ga = A  + (size_t)(m0 + row) * K + k0 + (colb >> 1);
      const u16* gb = BT + (size_t)(n0 + row) * K + k0 + (colb >> 1);
      __builtin_amdgcn_global_load_lds(
          (__attribute__((address_space(1))) void*)ga,
          (__attribute__((address_space(3))) void*)((char*)Als + r * 4096 + w * 1024),
          16, 0, 0);
      __builtin_amdgcn_global_load_lds(
          (__attribute__((address_space(1))) void*)gb,
          (__attribute__((address_space(3))) void*)((char*)Bls + r * 4096 + w * 1024),
          16, 0, 0);
    }
    __syncthreads();

    short8 af[4], bfr[4];
#pragma unroll
    for (int mi = 0; mi < 4; ++mi)
      af[mi] = *(const short8*)(Als + (wr + mi * 16 + lc) * 32 + quad * 8);
#pragma unroll
    for (int ni = 0; ni < 4; ++ni)
      bfr[ni] = *(const short8*)(Bls + (wc + ni * 16 + lc) * 32 + quad * 8);
#pragma unroll
    for (int mi = 0; mi < 4; ++mi)
#pragma unroll
      for (int ni = 0; ni < 4; ++ni)
        acc[mi][ni] = __builtin_amdgcn_mfma_f32_16x16x32_bf16(
            af[mi], bfr[ni], acc[mi][ni], 0, 0, 0);
  }

#pragma unroll
  for (int mi = 0; mi < 4; ++mi)
#pragma unroll
    for (int ni = 0; ni < 4; ++ni)
#pragma unroll
      for (int r = 0; r < 4; ++r) {
        const int row = m0 + wr + mi * 16 + quad * 4 + r;
        const int col = n0 + wc + ni * 16 + lc;
        if (OUT_F32)
          ((float*)Cv)[(size_t)row * N + col] = acc[mi][ni][r];
        else
          ((u16*)Cv)[(size_t)row * N + col] = f2bf(acc[mi][ni][r]);
      }
}

// ---------------------------------------------------------------------------
// RoPE in-place on QKV (q cols 0..2047, k cols 2048..2559). fc fp32 [S][64][2].
// ---------------------------------------------------------------------------
__global__ __launch_bounds__(256) void rope_kernel(
    u16* __restrict__ qkv, const float* __restrict__ fc)
{
  const int id   = blockIdx.x * 256 + threadIdx.x;   // S*20*64 total
  const int d    = id & 63;
  const int rest = id >> 6;
  const int head = rest % 20;
  const int s    = rest / 20;
  const int col  = (head < 16) ? head * 128 + 2 * d
                               : 2048 + (head - 16) * 128 + 2 * d;
  u16* p = qkv + (size_t)s * QKV_N + col;
  const float a = bf2f(p[0]);
  const float b = bf2f(p[1]);
  const float c  = fc[s * 128 + d * 2 + 0];
  const float sn = fc[s * 128 + d * 2 + 1];
  p[0] = f2bf(a * c - b * sn);
  p[1] = f2bf(a * sn + b * c);
}

// ---------------------------------------------------------------------------
// Flash attention, split-K x2 (flash-decoding style). grid = (S/64, NH, 2).
// Each block: 4 independent waves x 16 q-rows, processes its half of the
// window's 64-key tiles. Emits unnormalized partial O (bf16) and per-row
// (m, l) fp32. attn_combine merges the two splits.
// ---------------------------------------------------------------------------
__global__ __launch_bounds__(256) void attn_kernel(
    const u16* __restrict__ qkv, const u16* __restrict__ vt,
    u16* __restrict__ Om, float2* __restrict__ Ml)
{
  __shared__ u16 P[4 * 16 * 72];      // per-wave strips [w*16+m][key], pad 8

  const int tid  = threadIdx.x;
  const int lane = tid & 63;
  const int w    = tid >> 6;
  const int quad = lane >> 4;
  const int lc   = lane & 15;
  const int q0   = blockIdx.x * 64;
  const int h    = blockIdx.y;
  const int z    = blockIdx.z;
  const int kvh  = h >> 2;
  const int rb   = q0 + w * 16;       // wave's first q row

  // Q fragments (A-operand): m=lc -> row rb+lc; k = ks*32 + quad*8
  short8 qf[4];
  {
    const u16* qp = qkv + (size_t)(rb + lc) * QKV_N + h * HD + quad * 8;
#pragma unroll
    for (int ks = 0; ks < 4; ++ks) qf[ks] = *(const short8*)(qp + ks * 32);
  }

  float4v o[8];
#pragma unroll
  for (int i = 0; i < 8; ++i) o[i] = (float4v){0.f, 0.f, 0.f, 0.f};
  float mrow[4], lrow[4];
#pragma unroll
  for (int r = 0; r < 4; ++r) { mrow[r] = NEG_BIG; lrow[r] = 0.f; }

  int jmin = rb - (WIN - 1); if (jmin < 0) jmin = 0;
  const int kt_begin = jmin >> 6;
  const int kt_end   = rb >> 6;
  const int n        = kt_end - kt_begin + 1;      // 1..17
  const int half     = (n + 1) >> 1;
  const int ktb      = z ? (kt_begin + half) : kt_begin;
  const int kte      = z ? kt_end : (kt_begin + half - 1);

  const u16* vbase = vt + (size_t)kvh * HD * S_LEN;

  for (int kt = ktb; kt <= kte; ++kt) {
    const int k0 = kt * 64;

    // S = Q K^T : wave's 16 rows x 64 keys (K direct from global)
    float4v sacc[4];
#pragma unroll
    for (int i = 0; i < 4; ++i) sacc[i] = (float4v){0.f, 0.f, 0.f, 0.f};
#pragma unroll
    for (int ks = 0; ks < 4; ++ks) {
#pragma unroll
      for (int nt = 0; nt < 4; ++nt) {
        const u16* kp = qkv + (size_t)(k0 + nt * 16 + lc) * QKV_N + 2048 + kvh * HD
                        + ks * 32 + quad * 8;
        short8 kb = *(const short8*)kp;
        sacc[nt] = __builtin_amdgcn_mfma_f32_16x16x32_bf16(qf[ks], kb, sacc[nt], 0, 0, 0);
      }
    }

    // mask + scale; row max
    const bool full = (k0 + 63 <= rb) && ((rb + 15 - k0) <= WIN - 1);
    float sv[4][4];
    bool  ok[4][4];
    float rmax[4] = {NEG_BIG, NEG_BIG, NEG_BIG, NEG_BIG};
#pragma unroll
    for (int nt = 0; nt < 4; ++nt) {
      const int j = k0 + nt * 16 + lc;
#pragma unroll
      for (int r = 0; r < 4; ++r) {
        const int i = rb + quad * 4 + r;
        const bool valid = full || ((j <= i) && (i - j < WIN));
        float s = sacc[nt][r] * SM_SCALE;
        s = valid ? s : NEG_BIG;
        sv[nt][r] = s;
        ok[nt][r] = valid;
        rmax[r] = fmaxf(rmax[r], s);
      }
    }
#pragma unroll
    for (int off = 1; off < 16; off <<= 1)
#pragma unroll
      for (int r = 0; r < 4; ++r)
        rmax[r] = fmaxf(rmax[r], __shfl_xor(rmax[r], off, 64));

    float alpha[4], rsum[4];
#pragma unroll
    for (int r = 0; r < 4; ++r) {
      const float mn = fmaxf(mrow[r], rmax[r]);
      alpha[r] = __expf(mrow[r] - mn);
      mrow[r] = mn;
      rsum[r] = 0.f;
    }
#pragma unroll
    for (int nt = 0; nt < 4; ++nt)
#pragma unroll
      for (int r = 0; r < 4; ++r) {
        const float p = ok[nt][r] ? __expf(sv[nt][r] - mrow[r]) : 0.f;
        rsum[r] += p;
        P[(w * 16 + quad * 4 + r) * 72 + nt * 16 + lc] = f2bf(p);
      }
#pragma unroll
    for (int off = 1; off < 16; off <<= 1)
#pragma unroll
      for (int r = 0; r < 4; ++r)
        rsum[r] += __shfl_xor(rsum[r], off, 64);
#pragma unroll
    for (int r = 0; r < 4; ++r) lrow[r] = lrow[r] * alpha[r] + rsum[r];
#pragma unroll
    for (int i = 0; i < 8; ++i)
#pragma unroll
      for (int r = 0; r < 4; ++r) o[i][r] *= alpha[r];

    // O += P V : A = P strip (per-wave LDS), B = VT global [hd][s]
#pragma unroll
    for (int ktk = 0; ktk < 2; ++ktk) {
      short8 pa = *(const short8*)(P + (w * 16 + lc) * 72 + ktk * 32 + quad * 8);
#pragma unroll
      for (int nt2 = 0; nt2 < 8; ++nt2) {
        const u16* vp = vbase + (size_t)(nt2 * 16 + lc) * S_LEN + k0 + ktk * 32 + quad * 8;
        short8 vb = *(const short8*)vp;
        o[nt2] = __builtin_amdgcn_mfma_f32_16x16x32_bf16(pa, vb, o[nt2], 0, 0, 0);
      }
    }
  }

  // epilogue: unnormalized partial O + (m, l)
  u16* obase = Om + (size_t)(z * NHQ + h) * S_LEN * HD;
#pragma unroll
  for (int r = 0; r < 4; ++r) {
    const int row = rb + quad * 4 + r;
    if (lc == 0) Ml[(size_t)(z * NHQ + h) * S_LEN + row] = make_float2(mrow[r], lrow[r]);
#pragma unroll
    for (int nt2 = 0; nt2 < 8; ++nt2)
      obase[(size_t)row * HD + nt2 * 16 + lc] = f2bf(o[nt2][r]);
  }
}

// ---------------------------------------------------------------------------
// Merge the two splits: ATTN[row][h*128+d] = (w0*O0 + w1*O1)/(w0*l0 + w1*l1).
// grid = S*NH*HD/8/256 = 2048 blocks.
// ---------------------------------------------------------------------------
__global__ __launch_bounds__(256) void attn_combine(
    const u16* __restrict__ Om, const float2* __restrict__ Ml,
    u16* __restrict__ attn)
{
  const int t    = blockIdx.x * 256 + threadIdx.x;   // 524288
  const int col8 = (t & 15) * 8;
  const int rh   = t >> 4;                           // h*2048 + row
  const int h    = rh >> 11;
  const int row  = rh & 2047;

  const float2 ml0 = Ml[(size_t)h * S_LEN + row];
  const float2 ml1 = Ml[(size_t)(NHQ + h) * S_LEN + row];
  const float mx = fmaxf(ml0.x, ml1.x);
  const float w0 = __expf(ml0.x - mx);
  const float w1 = __expf(ml1.x - mx);
  const float inv = 1.f / (w0 * ml0.y + w1 * ml1.y);
  const float s0 = w0 * inv, s1 = w1 * inv;

  const u16* p0 = Om + ((size_t)h * S_LEN + row) * HD + col8;
  const u16* p1 = p0 + (size_t)NHQ * S_LEN * HD;
  short8 a = *(const short8*)p0;
  short8 b = *(const short8*)p1;
  u16* d = attn + (size_t)row * 2048 + h * HD + col8;
#pragma unroll
  for (int j = 0; j < 8; ++j)
    d[j] = f2bf(s0 * bf2f((u16)a[j]) + s1 * bf2f((u16)b[j]));
}

// ---------------------------------------------------------------------------
extern "C" void kernel_launch(void* const* d_in, const int* in_sizes, int n_in,
                              void* d_out, int out_size, void* d_ws, size_t ws_size,
                              hipStream_t stream) {
  const float* hs = (const float*)d_in[0];   // fp32
  const float* fc = (const float*)d_in[1];   // fp32
  // d_in[2] attention_mask all-true; d_in[3] causal analytic; d_in[4] arange
  const float* Wq = (const float*)d_in[5];
  const float* Wk = (const float*)d_in[6];
  const float* Wv = (const float*)d_in[7];
  const float* Wo = (const float*)d_in[8];
  float* outp = (float*)d_out;               // fp32 output

  u16* hsB   = (u16*)d_ws;                           // 2048 x 2048
  u16* WqkvT = hsB   + (size_t)2048 * 2048;          // 3072 x 2048
  u16* WoT   = WqkvT + (size_t)3072 * 2048;          // 2048 x 2048
  u16* QKV   = WoT   + (size_t)2048 * 2048;          // 2048 x 3072
  u16* ATTN  = QKV   + (size_t)2048 * 3072;          // 2048 x 2048
  u16* VT    = ATTN  + (size_t)2048 * 2048;          // 4 x 128 x 2048
  u16* Om    = VT    + (size_t)4 * 128 * 2048;       // 2 x 16 x 2048 x 128
  float2* Ml = (float2*)(Om + (size_t)2 * NHQ * S_LEN * HD);  // 2 x 16 x 2048

  dim3 blk(256);
  cvt_f32_bf16<<<dim3(2048 * 2048 / 1024), blk, 0, stream>>>(hs, hsB, 2048 * 2048);
  transpose_f32_bf16<<<dim3(2048 / 32, 2048 / 32), blk, 0, stream>>>(Wq, WqkvT, 2048, 2048);
  transpose_f32_bf16<<<dim3(512 / 32, 2048 / 32), blk, 0, stream>>>(Wk, WqkvT + (size_t)2048 * 2048, 2048, 512);
  transpose_f32_bf16<<<dim3(512 / 32, 2048 / 32), blk, 0, stream>>>(Wv, WqkvT + (size_t)2560 * 2048, 2048, 512);
  transpose_f32_bf16<<<dim3(2048 / 32, 2048 / 32), blk, 0, stream>>>(Wo, WoT, 2048, 2048);

  gemm_bt<false><<<dim3(3072 / 128, 2048 / 128), blk, 0, stream>>>(hsB, WqkvT, QKV, 2048, 3072, 2048);
  rope_kernel<<<dim3(2048 * 1280 / 256), blk, 0, stream>>>(QKV, fc);
  v_transpose<<<dim3(2048 / 32, HD / 32, NKVH), blk, 0, stream>>>(QKV, VT);
  attn_kernel<<<dim3(2048 / 64, NHQ, 2), blk, 0, stream>>>(QKV, VT, Om, Ml);
  attn_combine<<<dim3(2048), blk, 0, stream>>>(Om, Ml, ATTN);
  gemm_bt<true><<<dim3(2048 / 128, 2048 / 128), blk, 0, stream>>>(ATTN, WoT, outp, 2048, 2048, 2048);
}

// Round 8
// 286.916 us; speedup vs baseline: 1.2763x; 1.2763x over previous
//
#include <hip/hip_runtime.h>
#include <hip/hip_bf16.h>
#include <stdint.h>

#define S_LEN 2048
#define HDIM  2048
#define NHQ   16
#define NKVH  4
#define HD    128
#define WIN   1024
#define QKV_N 3072          // 2048 q | 512 k | 512 v
#define SM_SCALE 0.08838834764831845f
#define NEG_BIG  -1.0e30f

typedef __attribute__((ext_vector_type(8))) short short8;
typedef __attribute__((ext_vector_type(4))) float float4v;
typedef unsigned short u16;

static __device__ __forceinline__ float bf2f(u16 u) {
  union { unsigned int i; float f; } v; v.i = ((unsigned int)u) << 16; return v.f;
}
static __device__ __forceinline__ u16 f2bf(float f) {
  union { float f; unsigned int i; } v; v.f = f;
  unsigned int x = v.i;
  return (u16)((x + 0x7fffu + ((x >> 16) & 1u)) >> 16);   // RNE, finite inputs
}

// ---------------------------------------------------------------------------
// fp32 -> bf16 elementwise convert (hidden_state). n divisible by 1024.
// ---------------------------------------------------------------------------
__global__ __launch_bounds__(256) void cvt_f32_bf16(
    const float* __restrict__ x, u16* __restrict__ y, int n)
{
  const int i = (blockIdx.x * 256 + threadIdx.x) * 4;
  if (i < n) {
    const float4 v = *(const float4*)(x + i);
    y[i + 0] = f2bf(v.x);
    y[i + 1] = f2bf(v.y);
    y[i + 2] = f2bf(v.z);
    y[i + 3] = f2bf(v.w);
  }
}

// ---------------------------------------------------------------------------
// Fused convert+transpose: W fp32 [K][N] -> WT bf16 [N][K].
// ---------------------------------------------------------------------------
__global__ __launch_bounds__(256) void transpose_f32_bf16(
    const float* __restrict__ W, u16* __restrict__ WT, int K, int N)
{
  __shared__ u16 t[32][33];
  const int n0 = blockIdx.x * 32, k0 = blockIdx.y * 32;
  const int tx = threadIdx.x & 31, ty = threadIdx.x >> 5;
#pragma unroll
  for (int i = 0; i < 4; ++i)
    t[ty + i * 8][tx] = f2bf(W[(size_t)(k0 + ty + i * 8) * N + n0 + tx]);
  __syncthreads();
#pragma unroll
  for (int i = 0; i < 4; ++i)
    WT[(size_t)(n0 + ty + i * 8) * K + k0 + tx] = t[tx][ty + i * 8];
}

// ---------------------------------------------------------------------------
// K pack: QKV k-section -> tile-contiguous Kp[kvh][kt][key][chunk^(key&15)][8].
// 16B chunks XOR-swizzled so LDS b128 fragment reads are conflict-free.
// grid = (32 kt, 4 kvh), 256 threads, 4 chunks each.
// ---------------------------------------------------------------------------
__global__ __launch_bounds__(256) void kpack_kernel(
    const u16* __restrict__ qkv, u16* __restrict__ kp)
{
  const int kt  = blockIdx.x;
  const int kvh = blockIdx.y;
  u16* dst = kp + ((size_t)(kvh * 32 + kt)) * 64 * 128;
#pragma unroll
  for (int i = 0; i < 4; ++i) {
    const int cid = i * 256 + threadIdx.x;   // 0..1023
    const int key = cid >> 4;
    const int c   = cid & 15;
    short8 v = *(const short8*)(qkv + (size_t)(kt * 64 + key) * QKV_N
                                + 2048 + kvh * HD + c * 8);
    *(short8*)(dst + key * 128 + ((c ^ (key & 15)) * 8)) = v;
  }
}

// ---------------------------------------------------------------------------
// V pack (transpose): -> Vp[kvh][kt][hd][chunk^(hd&7)][8 keys].
// grid = (64 s-tiles, 4 h-tiles, 4 kvh), 256 threads.
// ---------------------------------------------------------------------------
__global__ __launch_bounds__(256) void vpack_kernel(
    const u16* __restrict__ qkv, u16* __restrict__ vp)
{
  __shared__ u16 t[32][33];
  const int s0  = blockIdx.x * 32;
  const int h0  = blockIdx.y * 32;
  const int kvh = blockIdx.z;
  const int tx = threadIdx.x & 31, ty = threadIdx.x >> 5;
  const int kt   = s0 >> 6;
  const int keyb = s0 & 63;          // 0 or 32
#pragma unroll
  for (int i = 0; i < 4; ++i)
    t[ty + i * 8][tx] = qkv[(size_t)(s0 + ty + i * 8) * QKV_N + 2560 + kvh * HD + h0 + tx];
  __syncthreads();
  u16* dst = vp + ((size_t)(kvh * 32 + kt)) * 128 * 64;
#pragma unroll
  for (int i = 0; i < 4; ++i) {
    const int hd   = h0 + ty + i * 8;
    const int keyl = keyb + tx;
    const int c    = (keyl >> 3) ^ (hd & 7);
    dst[hd * 64 + c * 8 + (keyl & 7)] = t[tx][ty + i * 8];
  }
}

// ---------------------------------------------------------------------------
// GEMM: C = A[M,K] * BT[N,K]^T, bf16 in, fp32 accum. m97 template.
// ---------------------------------------------------------------------------
template <bool OUT_F32>
__global__ __launch_bounds__(256) void gemm_bt(
    const u16* __restrict__ A, const u16* __restrict__ BT,
    void* __restrict__ Cv, int M, int N, int K)
{
  __shared__ u16 Als[128 * 32];
  __shared__ u16 Bls[128 * 32];

  const int tid  = threadIdx.x;
  const int lane = tid & 63;
  const int w    = tid >> 6;
  const int quad = lane >> 4;
  const int lc   = lane & 15;
  const int n0   = blockIdx.x * 128;
  const int m0   = blockIdx.y * 128;
  const int wr   = (w >> 1) * 64;
  const int wc   = (w & 1) * 64;

  float4v acc[4][4];
#pragma unroll
  for (int i = 0; i < 4; ++i)
#pragma unroll
    for (int j = 0; j < 4; ++j) acc[i][j] = (float4v){0.f, 0.f, 0.f, 0.f};

  const int offBase = w * 1024 + lane * 16;

  for (int k0 = 0; k0 < K; k0 += 32) {
    __syncthreads();
#pragma unroll
    for (int r = 0; r < 2; ++r) {
      const int off  = r * 4096 + offBase;
      const int row  = off >> 6;
      const int colb = off & 63;
      const u16* ga = A  + (size_t)(m0 + row) * K + k0 + (colb >> 1);
      const u16* gb = BT + (size_t)(n0 + row) * K + k0 + (colb >> 1);
      __builtin_amdgcn_global_load_lds(
          (__attribute__((address_space(1))) void*)ga,
          (__attribute__((address_space(3))) void*)((char*)Als + r * 4096 + w * 1024),
          16, 0, 0);
      __builtin_amdgcn_global_load_lds(
          (__attribute__((address_space(1))) void*)gb,
          (__attribute__((address_space(3))) void*)((char*)Bls + r * 4096 + w * 1024),
          16, 0, 0);
    }
    __syncthreads();

    short8 af[4], bfr[4];
#pragma unroll
    for (int mi = 0; mi < 4; ++mi)
      af[mi] = *(const short8*)(Als + (wr + mi * 16 + lc) * 32 + quad * 8);
#pragma unroll
    for (int ni = 0; ni < 4; ++ni)
      bfr[ni] = *(const short8*)(Bls + (wc + ni * 16 + lc) * 32 + quad * 8);
#pragma unroll
    for (int mi = 0; mi < 4; ++mi)
#pragma unroll
      for (int ni = 0; ni < 4; ++ni)
        acc[mi][ni] = __builtin_amdgcn_mfma_f32_16x16x32_bf16(
            af[mi], bfr[ni], acc[mi][ni], 0, 0, 0);
  }

#pragma unroll
  for (int mi = 0; mi < 4; ++mi)
#pragma unroll
    for (int ni = 0; ni < 4; ++ni)
#pragma unroll
      for (int r = 0; r < 4; ++r) {
        const int row = m0 + wr + mi * 16 + quad * 4 + r;
        const int col = n0 + wc + ni * 16 + lc;
        if (OUT_F32)
          ((float*)Cv)[(size_t)row * N + col] = acc[mi][ni][r];
        else
          ((u16*)Cv)[(size_t)row * N + col] = f2bf(acc[mi][ni][r]);
      }
}

// ---------------------------------------------------------------------------
// RoPE in-place on QKV (q cols 0..2047, k cols 2048..2559). fc fp32 [S][64][2].
// ---------------------------------------------------------------------------
__global__ __launch_bounds__(256) void rope_kernel(
    u16* __restrict__ qkv, const float* __restrict__ fc)
{
  const int id   = blockIdx.x * 256 + threadIdx.x;   // S*20*64 total
  const int d    = id & 63;
  const int rest = id >> 6;
  const int head = rest % 20;
  const int s    = rest / 20;
  const int col  = (head < 16) ? head * 128 + 2 * d
                               : 2048 + (head - 16) * 128 + 2 * d;
  u16* p = qkv + (size_t)s * QKV_N + col;
  const float a = bf2f(p[0]);
  const float b = bf2f(p[1]);
  const float c  = fc[s * 128 + d * 2 + 0];
  const float sn = fc[s * 128 + d * 2 + 1];
  p[0] = f2bf(a * c - b * sn);
  p[1] = f2bf(a * sn + b * c);
}

// ---------------------------------------------------------------------------
// Flash attention v3, m97-style: per 64-key tile, stage K (16KB) + V^T (16KB)
// into LDS with global_load_lds from tile-packed Kp/Vp, then ds_read_b128
// fragments + MFMA. All 4 waves share the staged tiles; per-wave softmax.
// grid = (S/64, NH), 256 threads.
// ---------------------------------------------------------------------------
__global__ __launch_bounds__(256) void attn_kernel(
    const u16* __restrict__ qkv, const u16* __restrict__ kp,
    const u16* __restrict__ vp, u16* __restrict__ out)
{
  __shared__ u16 Kls[64 * 128];       // [key][chunk^(key&15)][8]
  __shared__ u16 Vls[128 * 64];       // [hd][chunk^(hd&7)][8]
  __shared__ u16 P[4 * 16 * 72];      // per-wave strips [w*16+m][key], pad 8

  const int tid  = threadIdx.x;
  const int lane = tid & 63;
  const int w    = tid >> 6;
  const int quad = lane >> 4;
  const int lc   = lane & 15;
  const int q0   = blockIdx.x * 64;
  const int h    = blockIdx.y;
  const int kvh  = h >> 2;
  const int rb   = q0 + w * 16;       // wave's first q row

  // Q fragments (A-operand): m=lc -> row rb+lc; k = ks*32 + quad*8
  short8 qf[4];
  {
    const u16* qp = qkv + (size_t)(rb + lc) * QKV_N + h * HD + quad * 8;
#pragma unroll
    for (int ks = 0; ks < 4; ++ks) qf[ks] = *(const short8*)(qp + ks * 32);
  }

  float4v o[8];
#pragma unroll
  for (int i = 0; i < 8; ++i) o[i] = (float4v){0.f, 0.f, 0.f, 0.f};
  float mrow[4], lrow[4];
#pragma unroll
  for (int r = 0; r < 4; ++r) { mrow[r] = NEG_BIG; lrow[r] = 0.f; }

  // block-uniform tile range (union over waves)
  int jmin_blk = q0 - (WIN - 1); if (jmin_blk < 0) jmin_blk = 0;
  const int kt_begin = jmin_blk >> 6;
  const int kt_end   = q0 >> 6;

  const size_t tbase = (size_t)(kvh * 32) * 64 * 128;   // elems per kv-head block

  for (int kt = kt_begin; kt <= kt_end; ++kt) {
    const int k0 = kt * 64;

    __syncthreads();   // previous tile fully consumed
    {
      const u16* kg = kp + tbase + (size_t)kt * 64 * 128;
      const u16* vg = vp + tbase + (size_t)kt * 128 * 64;
#pragma unroll
      for (int i = 0; i < 4; ++i) {
        const int off = i * 4096 + tid * 16;   // bytes
        __builtin_amdgcn_global_load_lds(
            (__attribute__((address_space(1))) void*)((const char*)kg + off),
            (__attribute__((address_space(3))) void*)((char*)Kls + off), 16, 0, 0);
        __builtin_amdgcn_global_load_lds(
            (__attribute__((address_space(1))) void*)((const char*)vg + off),
            (__attribute__((address_space(3))) void*)((char*)Vls + off), 16, 0, 0);
      }
    }
    __syncthreads();   // staged data visible

    // wave-uniform skip: tile outside this wave's window
    if (k0 > rb + 15 || k0 + 63 < rb - (WIN - 1)) continue;

    // S = Q K^T : wave's 16 rows x 64 keys (K frags from LDS, swizzled)
    float4v sacc[4];
#pragma unroll
    for (int i = 0; i < 4; ++i) sacc[i] = (float4v){0.f, 0.f, 0.f, 0.f};
#pragma unroll
    for (int ks = 0; ks < 4; ++ks) {
#pragma unroll
      for (int nt = 0; nt < 4; ++nt) {
        const int key = nt * 16 + lc;
        const int c   = (ks * 4 + quad) ^ (key & 15);
        short8 kb = *(const short8*)(Kls + key * 128 + c * 8);
        sacc[nt] = __builtin_amdgcn_mfma_f32_16x16x32_bf16(qf[ks], kb, sacc[nt], 0, 0, 0);
      }
    }

    // mask + scale; row max
    const bool full = (k0 + 63 <= rb) && ((rb + 15 - k0) <= WIN - 1);
    float sv[4][4];
    bool  ok[4][4];
    float rmax[4] = {NEG_BIG, NEG_BIG, NEG_BIG, NEG_BIG};
#pragma unroll
    for (int nt = 0; nt < 4; ++nt) {
      const int j = k0 + nt * 16 + lc;
#pragma unroll
      for (int r = 0; r < 4; ++r) {
        const int i = rb + quad * 4 + r;
        const bool valid = full || ((j <= i) && (i - j < WIN));
        float s = sacc[nt][r] * SM_SCALE;
        s = valid ? s : NEG_BIG;
        sv[nt][r] = s;
        ok[nt][r] = valid;
        rmax[r] = fmaxf(rmax[r], s);
      }
    }
#pragma unroll
    for (int off = 1; off < 16; off <<= 1)
#pragma unroll
      for (int r = 0; r < 4; ++r)
        rmax[r] = fmaxf(rmax[r], __shfl_xor(rmax[r], off, 64));

    float alpha[4], rsum[4];
#pragma unroll
    for (int r = 0; r < 4; ++r) {
      const float mn = fmaxf(mrow[r], rmax[r]);
      alpha[r] = __expf(mrow[r] - mn);
      mrow[r] = mn;
      rsum[r] = 0.f;
    }
#pragma unroll
    for (int nt = 0; nt < 4; ++nt)
#pragma unroll
      for (int r = 0; r < 4; ++r) {
        const float p = ok[nt][r] ? __expf(sv[nt][r] - mrow[r]) : 0.f;
        rsum[r] += p;
        P[(w * 16 + quad * 4 + r) * 72 + nt * 16 + lc] = f2bf(p);
      }
#pragma unroll
    for (int off = 1; off < 16; off <<= 1)
#pragma unroll
      for (int r = 0; r < 4; ++r)
        rsum[r] += __shfl_xor(rsum[r], off, 64);
#pragma unroll
    for (int r = 0; r < 4; ++r) lrow[r] = lrow[r] * alpha[r] + rsum[r];
#pragma unroll
    for (int i = 0; i < 8; ++i)
#pragma unroll
      for (int r = 0; r < 4; ++r) o[i][r] *= alpha[r];

    // O += P V : A = P strip (per-wave LDS), B = V^T frags from LDS (swizzled)
#pragma unroll
    for (int ktk = 0; ktk < 2; ++ktk) {
      short8 pa = *(const short8*)(P + (w * 16 + lc) * 72 + ktk * 32 + quad * 8);
#pragma unroll
      for (int nt2 = 0; nt2 < 8; ++nt2) {
        const int hd = nt2 * 16 + lc;
        const int c  = (ktk * 4 + quad) ^ (hd & 7);
        short8 vb = *(const short8*)(Vls + hd * 64 + c * 8);
        o[nt2] = __builtin_amdgcn_mfma_f32_16x16x32_bf16(pa, vb, o[nt2], 0, 0, 0);
      }
    }
  }

  // epilogue
#pragma unroll
  for (int r = 0; r < 4; ++r) {
    const float inv = (lrow[r] > 0.f) ? (1.f / lrow[r]) : 0.f;
#pragma unroll
    for (int nt2 = 0; nt2 < 8; ++nt2) {
      const int row = rb + quad * 4 + r;
      const int col = h * HD + nt2 * 16 + lc;
      out[(size_t)row * 2048 + col] = f2bf(o[nt2][r] * inv);
    }
  }
}

// ---------------------------------------------------------------------------
extern "C" void kernel_launch(void* const* d_in, const int* in_sizes, int n_in,
                              void* d_out, int out_size, void* d_ws, size_t ws_size,
                              hipStream_t stream) {
  const float* hs = (const float*)d_in[0];   // fp32
  const float* fc = (const float*)d_in[1];   // fp32
  // d_in[2] attention_mask all-true; d_in[3] causal analytic; d_in[4] arange
  const float* Wq = (const float*)d_in[5];
  const float* Wk = (const float*)d_in[6];
  const float* Wv = (const float*)d_in[7];
  const float* Wo = (const float*)d_in[8];
  float* outp = (float*)d_out;               // fp32 output

  u16* hsB   = (u16*)d_ws;                           // 2048 x 2048
  u16* WqkvT = hsB   + (size_t)2048 * 2048;          // 3072 x 2048
  u16* WoT   = WqkvT + (size_t)3072 * 2048;          // 2048 x 2048
  u16* QKV   = WoT   + (size_t)2048 * 2048;          // 2048 x 3072
  u16* ATTN  = QKV   + (size_t)2048 * 3072;          // 2048 x 2048
  u16* Kp    = ATTN  + (size_t)2048 * 2048;          // 4 x 32 x 64 x 128
  u16* Vp    = Kp    + (size_t)4 * 2048 * 128;       // 4 x 32 x 128 x 64

  dim3 blk(256);
  cvt_f32_bf16<<<dim3(2048 * 2048 / 1024), blk, 0, stream>>>(hs, hsB, 2048 * 2048);
  transpose_f32_bf16<<<dim3(2048 / 32, 2048 / 32), blk, 0, stream>>>(Wq, WqkvT, 2048, 2048);
  transpose_f32_bf16<<<dim3(512 / 32, 2048 / 32), blk, 0, stream>>>(Wk, WqkvT + (size_t)2048 * 2048, 2048, 512);
  transpose_f32_bf16<<<dim3(512 / 32, 2048 / 32), blk, 0, stream>>>(Wv, WqkvT + (size_t)2560 * 2048, 2048, 512);
  transpose_f32_bf16<<<dim3(2048 / 32, 2048 / 32), blk, 0, stream>>>(Wo, WoT, 2048, 2048);

  gemm_bt<false><<<dim3(3072 / 128, 2048 / 128), blk, 0, stream>>>(hsB, WqkvT, QKV, 2048, 3072, 2048);
  rope_kernel<<<dim3(2048 * 1280 / 256), blk, 0, stream>>>(QKV, fc);
  kpack_kernel<<<dim3(32, NKVH), blk, 0, stream>>>(QKV, Kp);
  vpack_kernel<<<dim3(64, 4, NKVH), blk, 0, stream>>>(QKV, Vp);
  attn_kernel<<<dim3(2048 / 64, NHQ), blk, 0, stream>>>(QKV, Kp, Vp, ATTN);
  gemm_bt<true><<<dim3(2048 / 128, 2048 / 128), blk, 0, stream>>>(ATTN, WoT, outp, 2048, 2048, 2048);
}

// Round 9
// 273.179 us; speedup vs baseline: 1.3405x; 1.0503x over previous
//
#include <hip/hip_runtime.h>
#include <hip/hip_bf16.h>
#include <stdint.h>

#define S_LEN 2048
#define HDIM  2048
#define NHQ   16
#define NKVH  4
#define HD    128
#define WIN   1024
#define QKV_N 3072          // 2048 q | 512 k | 512 v
#define SM_SCALE 0.08838834764831845f
#define NEG_BIG  -1.0e30f

typedef __attribute__((ext_vector_type(8))) short short8;
typedef __attribute__((ext_vector_type(4))) float float4v;
typedef unsigned short u16;

static __device__ __forceinline__ float bf2f(u16 u) {
  union { unsigned int i; float f; } v; v.i = ((unsigned int)u) << 16; return v.f;
}
static __device__ __forceinline__ u16 f2bf(float f) {
  union { float f; unsigned int i; } v; v.f = f;
  unsigned int x = v.i;
  return (u16)((x + 0x7fffu + ((x >> 16) & 1u)) >> 16);   // RNE, finite inputs
}

// ---------------------------------------------------------------------------
// fp32 -> bf16 elementwise convert (hidden_state). n divisible by 1024.
// ---------------------------------------------------------------------------
__global__ __launch_bounds__(256) void cvt_f32_bf16(
    const float* __restrict__ x, u16* __restrict__ y, int n)
{
  const int i = (blockIdx.x * 256 + threadIdx.x) * 4;
  if (i < n) {
    const float4 v = *(const float4*)(x + i);
    y[i + 0] = f2bf(v.x);
    y[i + 1] = f2bf(v.y);
    y[i + 2] = f2bf(v.z);
    y[i + 3] = f2bf(v.w);
  }
}

// ---------------------------------------------------------------------------
// All weight transposes in ONE kernel. z=0: Wq|Wk|Wv -> WqkvT (96x64 tiles of
// 32x32); z=1: Wo -> WoT (64x64 tiles, x<64). fp32 in, bf16 out.
// ---------------------------------------------------------------------------
__global__ __launch_bounds__(256) void wtrans_all(
    const float* __restrict__ Wq, const float* __restrict__ Wk,
    const float* __restrict__ Wv, const float* __restrict__ Wo,
    u16* __restrict__ WqkvT, u16* __restrict__ WoT)
{
  __shared__ u16 t[32][33];
  const int tx = threadIdx.x & 31, ty = threadIdx.x >> 5;
  const int k0 = blockIdx.y * 32;

  const float* W; u16* DT; int nsrc, N;
  const int n0 = blockIdx.x * 32;
  if (blockIdx.z == 0) {
    if (n0 < 2048)      { W = Wq; nsrc = n0;        N = 2048; }
    else if (n0 < 2560) { W = Wk; nsrc = n0 - 2048; N = 512;  }
    else                { W = Wv; nsrc = n0 - 2560; N = 512;  }
    DT = WqkvT;
  } else {
    if (n0 >= 2048) return;
    W = Wo; nsrc = n0; N = 2048; DT = WoT;
  }

#pragma unroll
  for (int i = 0; i < 4; ++i)
    t[ty + i * 8][tx] = f2bf(W[(size_t)(k0 + ty + i * 8) * N + nsrc + tx]);
  __syncthreads();
#pragma unroll
  for (int i = 0; i < 4; ++i)
    DT[(size_t)(n0 + ty + i * 8) * 2048 + k0 + tx] = t[tx][ty + i * 8];
}

// ---------------------------------------------------------------------------
// GEMM: C = A[M,K] * BT[N,K]^T, bf16 in, fp32 accum. m97 staging, 128x64 tile
// (4 waves of 64x32) for uniform blocks/CU at these shapes.
// ---------------------------------------------------------------------------
template <bool OUT_F32>
__global__ __launch_bounds__(256) void gemm_bt(
    const u16* __restrict__ A, const u16* __restrict__ BT,
    void* __restrict__ Cv, int M, int N, int K)
{
  __shared__ u16 Als[128 * 32];   // 8 KB
  __shared__ u16 Bls[64 * 32];    // 4 KB

  const int tid  = threadIdx.x;
  const int lane = tid & 63;
  const int w    = tid >> 6;
  const int quad = lane >> 4;
  const int lc   = lane & 15;
  const int n0   = blockIdx.x * 64;
  const int m0   = blockIdx.y * 128;
  const int wr   = (w >> 1) * 64;
  const int wc   = (w & 1) * 32;

  float4v acc[4][2];
#pragma unroll
  for (int i = 0; i < 4; ++i)
#pragma unroll
    for (int j = 0; j < 2; ++j) acc[i][j] = (float4v){0.f, 0.f, 0.f, 0.f};

  for (int k0 = 0; k0 < K; k0 += 32) {
    __syncthreads();
#pragma unroll
    for (int r = 0; r < 2; ++r) {
      const int off  = r * 4096 + tid * 16;   // A: 8 KB
      const int row  = off >> 6;
      const int colb = off & 63;
      const u16* ga = A + (size_t)(m0 + row) * K + k0 + (colb >> 1);
      __builtin_amdgcn_global_load_lds(
          (__attribute__((address_space(1))) void*)ga,
          (__attribute__((address_space(3))) void*)((char*)Als + off), 16, 0, 0);
    }
    {
      const int off  = tid * 16;              // B: 4 KB
      const int row  = off >> 6;
      const int colb = off & 63;
      const u16* gb = BT + (size_t)(n0 + row) * K + k0 + (colb >> 1);
      __builtin_amdgcn_global_load_lds(
          (__attribute__((address_space(1))) void*)gb,
          (__attribute__((address_space(3))) void*)((char*)Bls + off), 16, 0, 0);
    }
    __syncthreads();

    short8 af[4], bfr[2];
#pragma unroll
    for (int mi = 0; mi < 4; ++mi)
      af[mi] = *(const short8*)(Als + (wr + mi * 16 + lc) * 32 + quad * 8);
#pragma unroll
    for (int ni = 0; ni < 2; ++ni)
      bfr[ni] = *(const short8*)(Bls + (wc + ni * 16 + lc) * 32 + quad * 8);
#pragma unroll
    for (int mi = 0; mi < 4; ++mi)
#pragma unroll
      for (int ni = 0; ni < 2; ++ni)
        acc[mi][ni] = __builtin_amdgcn_mfma_f32_16x16x32_bf16(
            af[mi], bfr[ni], acc[mi][ni], 0, 0, 0);
  }

#pragma unroll
  for (int mi = 0; mi < 4; ++mi)
#pragma unroll
    for (int ni = 0; ni < 2; ++ni)
#pragma unroll
      for (int r = 0; r < 4; ++r) {
        const int row = m0 + wr + mi * 16 + quad * 4 + r;
        const int col = n0 + wc + ni * 16 + lc;
        if (OUT_F32)
          ((float*)Cv)[(size_t)row * N + col] = acc[mi][ni][r];
        else
          ((u16*)Cv)[(size_t)row * N + col] = f2bf(acc[mi][ni][r]);
      }
}

// ---------------------------------------------------------------------------
// Fused RoPE + K-pack. 1-D grid of 1152 blocks:
//  blocks [0,1024): rope Q in-place (8 pairs/thread, vectorized)
//  blocks [1024,1152): rope K + write tile-packed swizzled Kp[kvh][kt]
// ---------------------------------------------------------------------------
__global__ __launch_bounds__(256) void rope_pack(
    u16* __restrict__ qkv, const float* __restrict__ fc,
    u16* __restrict__ kp)
{
  const int b = blockIdx.x;
  if (b < 1024) {
    // ---- rope Q: thread t handles 8 consecutive pairs (16 u16) ----
    const int t    = b * 256 + threadIdx.x;
    const int row  = t >> 7;                 // 128 threads/row
    const int head = (t & 127) >> 3;         // 16 heads
    const int d0   = (t & 7) * 8;            // 8 d's per thread
    u16* p = qkv + (size_t)row * QKV_N + head * HD + 2 * d0;
    short8 v0 = *(const short8*)p;
    short8 v1 = *(const short8*)(p + 8);
    const float2* f = (const float2*)(fc + row * 128) + d0;
    short8 o0, o1;
#pragma unroll
    for (int u = 0; u < 4; ++u) {
      const float2 cs = f[u];
      const float a = bf2f((u16)v0[2 * u]), bb = bf2f((u16)v0[2 * u + 1]);
      o0[2 * u]     = (short)f2bf(a * cs.x - bb * cs.y);
      o0[2 * u + 1] = (short)f2bf(a * cs.y + bb * cs.x);
    }
#pragma unroll
    for (int u = 0; u < 4; ++u) {
      const float2 cs = f[4 + u];
      const float a = bf2f((u16)v1[2 * u]), bb = bf2f((u16)v1[2 * u + 1]);
      o1[2 * u]     = (short)f2bf(a * cs.x - bb * cs.y);
      o1[2 * u + 1] = (short)f2bf(a * cs.y + bb * cs.x);
    }
    *(short8*)p = o0;
    *(short8*)(p + 8) = o1;
  } else {
    // ---- rope K + pack: block handles one (kvh, kt) 64x128 tile ----
    const int bb2 = b - 1024;
    const int kvh = bb2 >> 5;
    const int kt  = bb2 & 31;
    u16* dst = kp + ((size_t)(kvh * 32 + kt)) * 64 * 128;
#pragma unroll
    for (int i = 0; i < 4; ++i) {
      const int cid = i * 256 + threadIdx.x;   // 0..1023
      const int key = cid >> 4;
      const int c   = cid & 15;                // 16B chunk (8 elems = 4 pairs)
      const int s   = kt * 64 + key;
      short8 v = *(const short8*)(qkv + (size_t)s * QKV_N + 2048 + kvh * HD + c * 8);
      const float2* f = (const float2*)(fc + s * 128) + c * 4;
      short8 o;
#pragma unroll
      for (int u = 0; u < 4; ++u) {
        const float2 cs = f[u];
        const float a = bf2f((u16)v[2 * u]), bb3 = bf2f((u16)v[2 * u + 1]);
        o[2 * u]     = (short)f2bf(a * cs.x - bb3 * cs.y);
        o[2 * u + 1] = (short)f2bf(a * cs.y + bb3 * cs.x);
      }
      *(short8*)(dst + key * 128 + ((c ^ (key & 15)) * 8)) = o;
    }
  }
}

// ---------------------------------------------------------------------------
// V pack (transpose): -> Vp[kvh][kt][hd][chunk^(hd&7)][8 keys].
// grid = (64 s-tiles, 4 h-tiles, 4 kvh), 256 threads.
// ---------------------------------------------------------------------------
__global__ __launch_bounds__(256) void vpack_kernel(
    const u16* __restrict__ qkv, u16* __restrict__ vp)
{
  __shared__ u16 t[32][33];
  const int s0  = blockIdx.x * 32;
  const int h0  = blockIdx.y * 32;
  const int kvh = blockIdx.z;
  const int tx = threadIdx.x & 31, ty = threadIdx.x >> 5;
  const int kt   = s0 >> 6;
  const int keyb = s0 & 63;          // 0 or 32
#pragma unroll
  for (int i = 0; i < 4; ++i)
    t[ty + i * 8][tx] = qkv[(size_t)(s0 + ty + i * 8) * QKV_N + 2560 + kvh * HD + h0 + tx];
  __syncthreads();
  u16* dst = vp + ((size_t)(kvh * 32 + kt)) * 128 * 64;
#pragma unroll
  for (int i = 0; i < 4; ++i) {
    const int hd   = h0 + ty + i * 8;
    const int keyl = keyb + tx;
    const int c    = (keyl >> 3) ^ (hd & 7);
    dst[hd * 64 + c * 8 + (keyl & 7)] = t[tx][ty + i * 8];
  }
}

// ---------------------------------------------------------------------------
// Flash attention (round-8 structure, unchanged): per 64-key tile stage
// K (16KB) + V^T (16KB) via global_load_lds from packed Kp/Vp, ds_read_b128
// fragments + MFMA; per-wave online softmax. grid = (S/64, NH).
// ---------------------------------------------------------------------------
__global__ __launch_bounds__(256) void attn_kernel(
    const u16* __restrict__ qkv, const u16* __restrict__ kp,
    const u16* __restrict__ vp, u16* __restrict__ out)
{
  __shared__ u16 Kls[64 * 128];
  __shared__ u16 Vls[128 * 64];
  __shared__ u16 P[4 * 16 * 72];

  const int tid  = threadIdx.x;
  const int lane = tid & 63;
  const int w    = tid >> 6;
  const int quad = lane >> 4;
  const int lc   = lane & 15;
  const int q0   = blockIdx.x * 64;
  const int h    = blockIdx.y;
  const int kvh  = h >> 2;
  const int rb   = q0 + w * 16;

  short8 qf[4];
  {
    const u16* qp = qkv + (size_t)(rb + lc) * QKV_N + h * HD + quad * 8;
#pragma unroll
    for (int ks = 0; ks < 4; ++ks) qf[ks] = *(const short8*)(qp + ks * 32);
  }

  float4v o[8];
#pragma unroll
  for (int i = 0; i < 8; ++i) o[i] = (float4v){0.f, 0.f, 0.f, 0.f};
  float mrow[4], lrow[4];
#pragma unroll
  for (int r = 0; r < 4; ++r) { mrow[r] = NEG_BIG; lrow[r] = 0.f; }

  int jmin_blk = q0 - (WIN - 1); if (jmin_blk < 0) jmin_blk = 0;
  const int kt_begin = jmin_blk >> 6;
  const int kt_end   = q0 >> 6;

  const size_t tbase = (size_t)(kvh * 32) * 64 * 128;

  for (int kt = kt_begin; kt <= kt_end; ++kt) {
    const int k0 = kt * 64;

    __syncthreads();
    {
      const u16* kg = kp + tbase + (size_t)kt * 64 * 128;
      const u16* vg = vp + tbase + (size_t)kt * 128 * 64;
#pragma unroll
      for (int i = 0; i < 4; ++i) {
        const int off = i * 4096 + tid * 16;
        __builtin_amdgcn_global_load_lds(
            (__attribute__((address_space(1))) void*)((const char*)kg + off),
            (__attribute__((address_space(3))) void*)((char*)Kls + off), 16, 0, 0);
        __builtin_amdgcn_global_load_lds(
            (__attribute__((address_space(1))) void*)((const char*)vg + off),
            (__attribute__((address_space(3))) void*)((char*)Vls + off), 16, 0, 0);
      }
    }
    __syncthreads();

    if (k0 > rb + 15 || k0 + 63 < rb - (WIN - 1)) continue;

    float4v sacc[4];
#pragma unroll
    for (int i = 0; i < 4; ++i) sacc[i] = (float4v){0.f, 0.f, 0.f, 0.f};
#pragma unroll
    for (int ks = 0; ks < 4; ++ks) {
#pragma unroll
      for (int nt = 0; nt < 4; ++nt) {
        const int key = nt * 16 + lc;
        const int c   = (ks * 4 + quad) ^ (key & 15);
        short8 kb = *(const short8*)(Kls + key * 128 + c * 8);
        sacc[nt] = __builtin_amdgcn_mfma_f32_16x16x32_bf16(qf[ks], kb, sacc[nt], 0, 0, 0);
      }
    }

    const bool full = (k0 + 63 <= rb) && ((rb + 15 - k0) <= WIN - 1);
    float sv[4][4];
    bool  ok[4][4];
    float rmax[4] = {NEG_BIG, NEG_BIG, NEG_BIG, NEG_BIG};
#pragma unroll
    for (int nt = 0; nt < 4; ++nt) {
      const int j = k0 + nt * 16 + lc;
#pragma unroll
      for (int r = 0; r < 4; ++r) {
        const int i = rb + quad * 4 + r;
        const bool valid = full || ((j <= i) && (i - j < WIN));
        float s = sacc[nt][r] * SM_SCALE;
        s = valid ? s : NEG_BIG;
        sv[nt][r] = s;
        ok[nt][r] = valid;
        rmax[r] = fmaxf(rmax[r], s);
      }
    }
#pragma unroll
    for (int off = 1; off < 16; off <<= 1)
#pragma unroll
      for (int r = 0; r < 4; ++r)
        rmax[r] = fmaxf(rmax[r], __shfl_xor(rmax[r], off, 64));

    float alpha[4], rsum[4];
#pragma unroll
    for (int r = 0; r < 4; ++r) {
      const float mn = fmaxf(mrow[r], rmax[r]);
      alpha[r] = __expf(mrow[r] - mn);
      mrow[r] = mn;
      rsum[r] = 0.f;
    }
#pragma unroll
    for (int nt = 0; nt < 4; ++nt)
#pragma unroll
      for (int r = 0; r < 4; ++r) {
        const float p = ok[nt][r] ? __expf(sv[nt][r] - mrow[r]) : 0.f;
        rsum[r] += p;
        P[(w * 16 + quad * 4 + r) * 72 + nt * 16 + lc] = f2bf(p);
      }
#pragma unroll
    for (int off = 1; off < 16; off <<= 1)
#pragma unroll
      for (int r = 0; r < 4; ++r)
        rsum[r] += __shfl_xor(rsum[r], off, 64);
#pragma unroll
    for (int r = 0; r < 4; ++r) lrow[r] = lrow[r] * alpha[r] + rsum[r];
#pragma unroll
    for (int i = 0; i < 8; ++i)
#pragma unroll
      for (int r = 0; r < 4; ++r) o[i][r] *= alpha[r];

#pragma unroll
    for (int ktk = 0; ktk < 2; ++ktk) {
      short8 pa = *(const short8*)(P + (w * 16 + lc) * 72 + ktk * 32 + quad * 8);
#pragma unroll
      for (int nt2 = 0; nt2 < 8; ++nt2) {
        const int hd = nt2 * 16 + lc;
        const int c  = (ktk * 4 + quad) ^ (hd & 7);
        short8 vb = *(const short8*)(Vls + hd * 64 + c * 8);
        o[nt2] = __builtin_amdgcn_mfma_f32_16x16x32_bf16(pa, vb, o[nt2], 0, 0, 0);
      }
    }
  }

#pragma unroll
  for (int r = 0; r < 4; ++r) {
    const float inv = (lrow[r] > 0.f) ? (1.f / lrow[r]) : 0.f;
#pragma unroll
    for (int nt2 = 0; nt2 < 8; ++nt2) {
      const int row = rb + quad * 4 + r;
      const int col = h * HD + nt2 * 16 + lc;
      out[(size_t)row * 2048 + col] = f2bf(o[nt2][r] * inv);
    }
  }
}

// ---------------------------------------------------------------------------
extern "C" void kernel_launch(void* const* d_in, const int* in_sizes, int n_in,
                              void* d_out, int out_size, void* d_ws, size_t ws_size,
                              hipStream_t stream) {
  const float* hs = (const float*)d_in[0];   // fp32
  const float* fc = (const float*)d_in[1];   // fp32
  // d_in[2] attention_mask all-true; d_in[3] causal analytic; d_in[4] arange
  const float* Wq = (const float*)d_in[5];
  const float* Wk = (const float*)d_in[6];
  const float* Wv = (const float*)d_in[7];
  const float* Wo = (const float*)d_in[8];
  float* outp = (float*)d_out;               // fp32 output

  u16* hsB   = (u16*)d_ws;                           // 2048 x 2048
  u16* WqkvT = hsB   + (size_t)2048 * 2048;          // 3072 x 2048
  u16* WoT   = WqkvT + (size_t)3072 * 2048;          // 2048 x 2048
  u16* QKV   = WoT   + (size_t)2048 * 2048;          // 2048 x 3072
  u16* ATTN  = QKV   + (size_t)2048 * 3072;          // 2048 x 2048
  u16* Kp    = ATTN  + (size_t)2048 * 2048;          // 4 x 32 x 64 x 128
  u16* Vp    = Kp    + (size_t)4 * 2048 * 128;       // 4 x 32 x 128 x 64

  dim3 blk(256);
  cvt_f32_bf16<<<dim3(2048 * 2048 / 1024), blk, 0, stream>>>(hs, hsB, 2048 * 2048);
  wtrans_all<<<dim3(96, 64, 2), blk, 0, stream>>>(Wq, Wk, Wv, Wo, WqkvT, WoT);

  gemm_bt<false><<<dim3(3072 / 64, 2048 / 128), blk, 0, stream>>>(hsB, WqkvT, QKV, 2048, 3072, 2048);
  rope_pack<<<dim3(1152), blk, 0, stream>>>(QKV, fc, Kp);
  vpack_kernel<<<dim3(64, 4, NKVH), blk, 0, stream>>>(QKV, Vp);
  attn_kernel<<<dim3(2048 / 64, NHQ), blk, 0, stream>>>(QKV, Kp, Vp, ATTN);
  gemm_bt<true><<<dim3(2048 / 64, 2048 / 128), blk, 0, stream>>>(ATTN, WoT, outp, 2048, 2048, 2048);
}

// Round 10
// 265.693 us; speedup vs baseline: 1.3783x; 1.0282x over previous
//
#include <hip/hip_runtime.h>
#include <hip/hip_bf16.h>
#include <stdint.h>

#define S_LEN 2048
#define HDIM  2048
#define NHQ   16
#define NKVH  4
#define HD    128
#define WIN   1024
#define QKV_N 3072          // 2048 q | 512 k | 512 v
#define SM_SCALE 0.08838834764831845f
#define NEG_BIG  -1.0e30f

typedef __attribute__((ext_vector_type(8))) short short8;
typedef __attribute__((ext_vector_type(4))) float float4v;
typedef unsigned short u16;

static __device__ __forceinline__ float bf2f(u16 u) {
  union { unsigned int i; float f; } v; v.i = ((unsigned int)u) << 16; return v.f;
}
static __device__ __forceinline__ u16 f2bf(float f) {
  union { float f; unsigned int i; } v; v.f = f;
  unsigned int x = v.i;
  return (u16)((x + 0x7fffu + ((x >> 16) & 1u)) >> 16);   // RNE, finite inputs
}

// ---------------------------------------------------------------------------
// hidden_state pack: fp32 [2048][2048] -> Apk[mblk 16][kstep 64] tiles of
// 8KB, each [kc 4][m 128][8] bf16 (k-major, conflict-free fragment reads).
// grid = 1024 (mblk*64 + kstep), 256 threads x 2 chunks.
// ---------------------------------------------------------------------------
__global__ __launch_bounds__(256) void hs_pack(
    const float* __restrict__ x, u16* __restrict__ y)
{
  const int b = blockIdx.x;
  u16* dst = y + (size_t)b * 4096;
  const int mb = b >> 6, ks = b & 63;
#pragma unroll
  for (int i = 0; i < 2; ++i) {
    const int cid = i * 256 + threadIdx.x;   // 0..511
    const int kc  = cid & 3;
    const int m   = cid >> 2;
    const float* src = x + ((size_t)(mb * 128 + m)) * 2048 + ks * 32 + kc * 8;
    const float4 v0 = *(const float4*)src;
    const float4 v1 = *(const float4*)(src + 4);
    short8 o;
    o[0] = (short)f2bf(v0.x); o[1] = (short)f2bf(v0.y);
    o[2] = (short)f2bf(v0.z); o[3] = (short)f2bf(v0.w);
    o[4] = (short)f2bf(v1.x); o[5] = (short)f2bf(v1.y);
    o[6] = (short)f2bf(v1.z); o[7] = (short)f2bf(v1.w);
    *(short8*)(dst + (kc * 128 + m) * 8) = o;
  }
}

// ---------------------------------------------------------------------------
// Weight transposes -> packed B layout. Bpk[nblk][kstep] tiles of 4KB,
// each [kc 4][n 64][8]. z=0: Wq|Wk|Wv -> WqkvT; z=1: Wo -> WoT.
// ---------------------------------------------------------------------------
__global__ __launch_bounds__(256) void wtrans_all(
    const float* __restrict__ Wq, const float* __restrict__ Wk,
    const float* __restrict__ Wv, const float* __restrict__ Wo,
    u16* __restrict__ WqkvT, u16* __restrict__ WoT)
{
  __shared__ u16 t[32][33];
  const int tx = threadIdx.x & 31, ty = threadIdx.x >> 5;
  const int k0 = blockIdx.y * 32;           // one kstep
  const int n0 = blockIdx.x * 32;

  const float* W; u16* DT; int nsrc, N;
  if (blockIdx.z == 0) {
    if (n0 < 2048)      { W = Wq; nsrc = n0;        N = 2048; }
    else if (n0 < 2560) { W = Wk; nsrc = n0 - 2048; N = 512;  }
    else                { W = Wv; nsrc = n0 - 2560; N = 512;  }
    DT = WqkvT;
  } else {
    if (n0 >= 2048) return;
    W = Wo; nsrc = n0; N = 2048; DT = WoT;
  }

#pragma unroll
  for (int i = 0; i < 4; ++i)
    t[ty + i * 8][tx] = f2bf(W[(size_t)(k0 + ty + i * 8) * N + nsrc + tx]);
  __syncthreads();
  const int kstep = blockIdx.y;
  const int kc = tx >> 3, e = tx & 7;
#pragma unroll
  for (int i = 0; i < 4; ++i) {
    const int n = n0 + ty + i * 8;
    DT[((size_t)((n >> 6) * 64 + kstep)) * 2048 + kc * 512 + (n & 63) * 8 + e]
        = t[tx][ty + i * 8];
  }
}

// ---------------------------------------------------------------------------
// GEMM on packed operands: C = A*B^T, bf16 in, fp32 accum. 128x64 tile,
// 4 waves of 64x32. Staging = contiguous 8KB/4KB DMA; fragment reads are
// k-major -> bank-conflict-free. M,K mult of 128/32; N mult of 64.
// ---------------------------------------------------------------------------
template <bool OUT_F32>
__global__ __launch_bounds__(256) void gemm_bt(
    const u16* __restrict__ Apk, const u16* __restrict__ Bpk,
    void* __restrict__ Cv, int M, int N, int K)
{
  __shared__ u16 Als[4096];   // [kc 4][m 128][8]  8 KB
  __shared__ u16 Bls[2048];   // [kc 4][n 64][8]   4 KB

  const int tid  = threadIdx.x;
  const int lane = tid & 63;
  const int w    = tid >> 6;
  const int quad = lane >> 4;
  const int lc   = lane & 15;
  const int n0   = blockIdx.x * 64;
  const int m0   = blockIdx.y * 128;
  const int wr   = (w >> 1) * 64;
  const int wc   = (w & 1) * 32;
  const int ktiles = K >> 5;

  float4v acc[4][2];
#pragma unroll
  for (int i = 0; i < 4; ++i)
#pragma unroll
    for (int j = 0; j < 2; ++j) acc[i][j] = (float4v){0.f, 0.f, 0.f, 0.f};

  for (int ks = 0; ks < ktiles; ++ks) {
    const char* ab = (const char*)(Apk + ((size_t)((m0 >> 7) * ktiles + ks)) * 4096);
    const char* bb = (const char*)(Bpk + ((size_t)((n0 >> 6) * ktiles + ks)) * 2048);
    __syncthreads();
#pragma unroll
    for (int r = 0; r < 2; ++r) {
      const int off = r * 4096 + tid * 16;
      __builtin_amdgcn_global_load_lds(
          (__attribute__((address_space(1))) void*)(ab + off),
          (__attribute__((address_space(3))) void*)((char*)Als + off), 16, 0, 0);
    }
    {
      const int off = tid * 16;
      __builtin_amdgcn_global_load_lds(
          (__attribute__((address_space(1))) void*)(bb + off),
          (__attribute__((address_space(3))) void*)((char*)Bls + off), 16, 0, 0);
    }
    __syncthreads();

    short8 af[4], bfr[2];
#pragma unroll
    for (int mi = 0; mi < 4; ++mi)
      af[mi] = *(const short8*)(Als + quad * 1024 + (wr + mi * 16 + lc) * 8);
#pragma unroll
    for (int ni = 0; ni < 2; ++ni)
      bfr[ni] = *(const short8*)(Bls + quad * 512 + (wc + ni * 16 + lc) * 8);
#pragma unroll
    for (int mi = 0; mi < 4; ++mi)
#pragma unroll
      for (int ni = 0; ni < 2; ++ni)
        acc[mi][ni] = __builtin_amdgcn_mfma_f32_16x16x32_bf16(
            af[mi], bfr[ni], acc[mi][ni], 0, 0, 0);
  }

#pragma unroll
  for (int mi = 0; mi < 4; ++mi)
#pragma unroll
    for (int ni = 0; ni < 2; ++ni)
#pragma unroll
      for (int r = 0; r < 4; ++r) {
        const int row = m0 + wr + mi * 16 + quad * 4 + r;
        const int col = n0 + wc + ni * 16 + lc;
        if (OUT_F32)
          ((float*)Cv)[(size_t)row * N + col] = acc[mi][ni][r];
        else
          ((u16*)Cv)[(size_t)row * N + col] = f2bf(acc[mi][ni][r]);
      }
}

// ---------------------------------------------------------------------------
// Fused RoPE + K-pack (unchanged from round 9).
// ---------------------------------------------------------------------------
__global__ __launch_bounds__(256) void rope_pack(
    u16* __restrict__ qkv, const float* __restrict__ fc,
    u16* __restrict__ kp)
{
  const int b = blockIdx.x;
  if (b < 1024) {
    const int t    = b * 256 + threadIdx.x;
    const int row  = t >> 7;
    const int head = (t & 127) >> 3;
    const int d0   = (t & 7) * 8;
    u16* p = qkv + (size_t)row * QKV_N + head * HD + 2 * d0;
    short8 v0 = *(const short8*)p;
    short8 v1 = *(const short8*)(p + 8);
    const float2* f = (const float2*)(fc + row * 128) + d0;
    short8 o0, o1;
#pragma unroll
    for (int u = 0; u < 4; ++u) {
      const float2 cs = f[u];
      const float a = bf2f((u16)v0[2 * u]), bb = bf2f((u16)v0[2 * u + 1]);
      o0[2 * u]     = (short)f2bf(a * cs.x - bb * cs.y);
      o0[2 * u + 1] = (short)f2bf(a * cs.y + bb * cs.x);
    }
#pragma unroll
    for (int u = 0; u < 4; ++u) {
      const float2 cs = f[4 + u];
      const float a = bf2f((u16)v1[2 * u]), bb = bf2f((u16)v1[2 * u + 1]);
      o1[2 * u]     = (short)f2bf(a * cs.x - bb * cs.y);
      o1[2 * u + 1] = (short)f2bf(a * cs.y + bb * cs.x);
    }
    *(short8*)p = o0;
    *(short8*)(p + 8) = o1;
  } else {
    const int bb2 = b - 1024;
    const int kvh = bb2 >> 5;
    const int kt  = bb2 & 31;
    u16* dst = kp + ((size_t)(kvh * 32 + kt)) * 64 * 128;
#pragma unroll
    for (int i = 0; i < 4; ++i) {
      const int cid = i * 256 + threadIdx.x;
      const int key = cid >> 4;
      const int c   = cid & 15;
      const int s   = kt * 64 + key;
      short8 v = *(const short8*)(qkv + (size_t)s * QKV_N + 2048 + kvh * HD + c * 8);
      const float2* f = (const float2*)(fc + s * 128) + c * 4;
      short8 o;
#pragma unroll
      for (int u = 0; u < 4; ++u) {
        const float2 cs = f[u];
        const float a = bf2f((u16)v[2 * u]), bb3 = bf2f((u16)v[2 * u + 1]);
        o[2 * u]     = (short)f2bf(a * cs.x - bb3 * cs.y);
        o[2 * u + 1] = (short)f2bf(a * cs.y + bb3 * cs.x);
      }
      *(short8*)(dst + key * 128 + ((c ^ (key & 15)) * 8)) = o;
    }
  }
}

// ---------------------------------------------------------------------------
// V pack (unchanged): -> Vp[kvh][kt][hd][chunk^(hd&7)][8 keys].
// ---------------------------------------------------------------------------
__global__ __launch_bounds__(256) void vpack_kernel(
    const u16* __restrict__ qkv, u16* __restrict__ vp)
{
  __shared__ u16 t[32][33];
  const int s0  = blockIdx.x * 32;
  const int h0  = blockIdx.y * 32;
  const int kvh = blockIdx.z;
  const int tx = threadIdx.x & 31, ty = threadIdx.x >> 5;
  const int kt   = s0 >> 6;
  const int keyb = s0 & 63;
#pragma unroll
  for (int i = 0; i < 4; ++i)
    t[ty + i * 8][tx] = qkv[(size_t)(s0 + ty + i * 8) * QKV_N + 2560 + kvh * HD + h0 + tx];
  __syncthreads();
  u16* dst = vp + ((size_t)(kvh * 32 + kt)) * 128 * 64;
#pragma unroll
  for (int i = 0; i < 4; ++i) {
    const int hd   = h0 + ty + i * 8;
    const int keyl = keyb + tx;
    const int c    = (keyl >> 3) ^ (hd & 7);
    dst[hd * 64 + c * 8 + (keyl & 7)] = t[tx][ty + i * 8];
  }
}

// ---------------------------------------------------------------------------
// Flash attention (round-8 structure); epilogue now writes ATTN in the
// packed A layout for the out-projection GEMM. grid = (S/64, NH).
// ---------------------------------------------------------------------------
__global__ __launch_bounds__(256) void attn_kernel(
    const u16* __restrict__ qkv, const u16* __restrict__ kp,
    const u16* __restrict__ vp, u16* __restrict__ out)
{
  __shared__ u16 Kls[64 * 128];
  __shared__ u16 Vls[128 * 64];
  __shared__ u16 P[4 * 16 * 72];

  const int tid  = threadIdx.x;
  const int lane = tid & 63;
  const int w    = tid >> 6;
  const int quad = lane >> 4;
  const int lc   = lane & 15;
  const int q0   = blockIdx.x * 64;
  const int h    = blockIdx.y;
  const int kvh  = h >> 2;
  const int rb   = q0 + w * 16;

  short8 qf[4];
  {
    const u16* qp = qkv + (size_t)(rb + lc) * QKV_N + h * HD + quad * 8;
#pragma unroll
    for (int ks = 0; ks < 4; ++ks) qf[ks] = *(const short8*)(qp + ks * 32);
  }

  float4v o[8];
#pragma unroll
  for (int i = 0; i < 8; ++i) o[i] = (float4v){0.f, 0.f, 0.f, 0.f};
  float mrow[4], lrow[4];
#pragma unroll
  for (int r = 0; r < 4; ++r) { mrow[r] = NEG_BIG; lrow[r] = 0.f; }

  int jmin_blk = q0 - (WIN - 1); if (jmin_blk < 0) jmin_blk = 0;
  const int kt_begin = jmin_blk >> 6;
  const int kt_end   = q0 >> 6;

  const size_t tbase = (size_t)(kvh * 32) * 64 * 128;

  for (int kt = kt_begin; kt <= kt_end; ++kt) {
    const int k0 = kt * 64;

    __syncthreads();
    {
      const u16* kg = kp + tbase + (size_t)kt * 64 * 128;
      const u16* vg = vp + tbase + (size_t)kt * 128 * 64;
#pragma unroll
      for (int i = 0; i < 4; ++i) {
        const int off = i * 4096 + tid * 16;
        __builtin_amdgcn_global_load_lds(
            (__attribute__((address_space(1))) void*)((const char*)kg + off),
            (__attribute__((address_space(3))) void*)((char*)Kls + off), 16, 0, 0);
        __builtin_amdgcn_global_load_lds(
            (__attribute__((address_space(1))) void*)((const char*)vg + off),
            (__attribute__((address_space(3))) void*)((char*)Vls + off), 16, 0, 0);
      }
    }
    __syncthreads();

    if (k0 > rb + 15 || k0 + 63 < rb - (WIN - 1)) continue;

    float4v sacc[4];
#pragma unroll
    for (int i = 0; i < 4; ++i) sacc[i] = (float4v){0.f, 0.f, 0.f, 0.f};
#pragma unroll
    for (int ks = 0; ks < 4; ++ks) {
#pragma unroll
      for (int nt = 0; nt < 4; ++nt) {
        const int key = nt * 16 + lc;
        const int c   = (ks * 4 + quad) ^ (key & 15);
        short8 kb = *(const short8*)(Kls + key * 128 + c * 8);
        sacc[nt] = __builtin_amdgcn_mfma_f32_16x16x32_bf16(qf[ks], kb, sacc[nt], 0, 0, 0);
      }
    }

    const bool full = (k0 + 63 <= rb) && ((rb + 15 - k0) <= WIN - 1);
    float sv[4][4];
    bool  ok[4][4];
    float rmax[4] = {NEG_BIG, NEG_BIG, NEG_BIG, NEG_BIG};
#pragma unroll
    for (int nt = 0; nt < 4; ++nt) {
      const int j = k0 + nt * 16 + lc;
#pragma unroll
      for (int r = 0; r < 4; ++r) {
        const int i = rb + quad * 4 + r;
        const bool valid = full || ((j <= i) && (i - j < WIN));
        float s = sacc[nt][r] * SM_SCALE;
        s = valid ? s : NEG_BIG;
        sv[nt][r] = s;
        ok[nt][r] = valid;
        rmax[r] = fmaxf(rmax[r], s);
      }
    }
#pragma unroll
    for (int off = 1; off < 16; off <<= 1)
#pragma unroll
      for (int r = 0; r < 4; ++r)
        rmax[r] = fmaxf(rmax[r], __shfl_xor(rmax[r], off, 64));

    float alpha[4], rsum[4];
#pragma unroll
    for (int r = 0; r < 4; ++r) {
      const float mn = fmaxf(mrow[r], rmax[r]);
      alpha[r] = __expf(mrow[r] - mn);
      mrow[r] = mn;
      rsum[r] = 0.f;
    }
#pragma unroll
    for (int nt = 0; nt < 4; ++nt)
#pragma unroll
      for (int r = 0; r < 4; ++r) {
        const float p = ok[nt][r] ? __expf(sv[nt][r] - mrow[r]) : 0.f;
        rsum[r] += p;
        P[(w * 16 + quad * 4 + r) * 72 + nt * 16 + lc] = f2bf(p);
      }
#pragma unroll
    for (int off = 1; off < 16; off <<= 1)
#pragma unroll
      for (int r = 0; r < 4; ++r)
        rsum[r] += __shfl_xor(rsum[r], off, 64);
#pragma unroll
    for (int r = 0; r < 4; ++r) lrow[r] = lrow[r] * alpha[r] + rsum[r];
#pragma unroll
    for (int i = 0; i < 8; ++i)
#pragma unroll
      for (int r = 0; r < 4; ++r) o[i][r] *= alpha[r];

#pragma unroll
    for (int ktk = 0; ktk < 2; ++ktk) {
      short8 pa = *(const short8*)(P + (w * 16 + lc) * 72 + ktk * 32 + quad * 8);
#pragma unroll
      for (int nt2 = 0; nt2 < 8; ++nt2) {
        const int hd = nt2 * 16 + lc;
        const int c  = (ktk * 4 + quad) ^ (hd & 7);
        short8 vb = *(const short8*)(Vls + hd * 64 + c * 8);
        o[nt2] = __builtin_amdgcn_mfma_f32_16x16x32_bf16(pa, vb, o[nt2], 0, 0, 0);
      }
    }
  }

  // epilogue: write ATTN in packed-A layout [mblk][kstep][kc][m][8]
#pragma unroll
  for (int r = 0; r < 4; ++r) {
    const float inv = (lrow[r] > 0.f) ? (1.f / lrow[r]) : 0.f;
    const int row = rb + quad * 4 + r;
    const size_t mbase = (size_t)(row >> 7) * 64;
    const int m = row & 127;
#pragma unroll
    for (int nt2 = 0; nt2 < 8; ++nt2) {
      const int col = h * HD + nt2 * 16 + lc;
      const int kstep = col >> 5, kc = (col >> 3) & 3, e = col & 7;
      out[(mbase + kstep) * 4096 + kc * 1024 + m * 8 + e] = f2bf(o[nt2][r] * inv);
    }
  }
}

// ---------------------------------------------------------------------------
extern "C" void kernel_launch(void* const* d_in, const int* in_sizes, int n_in,
                              void* d_out, int out_size, void* d_ws, size_t ws_size,
                              hipStream_t stream) {
  const float* hs = (const float*)d_in[0];   // fp32
  const float* fc = (const float*)d_in[1];   // fp32
  // d_in[2] attention_mask all-true; d_in[3] causal analytic; d_in[4] arange
  const float* Wq = (const float*)d_in[5];
  const float* Wk = (const float*)d_in[6];
  const float* Wv = (const float*)d_in[7];
  const float* Wo = (const float*)d_in[8];
  float* outp = (float*)d_out;               // fp32 output

  u16* hsB   = (u16*)d_ws;                           // packed A, 2048x2048
  u16* WqkvT = hsB   + (size_t)2048 * 2048;          // packed B, 3072x2048
  u16* WoT   = WqkvT + (size_t)3072 * 2048;          // packed B, 2048x2048
  u16* QKV   = WoT   + (size_t)2048 * 2048;          // row-major 2048x3072
  u16* ATTN  = QKV   + (size_t)2048 * 3072;          // packed A, 2048x2048
  u16* Kp    = ATTN  + (size_t)2048 * 2048;          // 4 x 32 x 64 x 128
  u16* Vp    = Kp    + (size_t)4 * 2048 * 128;       // 4 x 32 x 128 x 64

  dim3 blk(256);
  hs_pack<<<dim3(1024), blk, 0, stream>>>(hs, hsB);
  wtrans_all<<<dim3(96, 64, 2), blk, 0, stream>>>(Wq, Wk, Wv, Wo, WqkvT, WoT);

  gemm_bt<false><<<dim3(3072 / 64, 2048 / 128), blk, 0, stream>>>(hsB, WqkvT, QKV, 2048, 3072, 2048);
  rope_pack<<<dim3(1152), blk, 0, stream>>>(QKV, fc, Kp);
  vpack_kernel<<<dim3(64, 4, NKVH), blk, 0, stream>>>(QKV, Vp);
  attn_kernel<<<dim3(2048 / 64, NHQ), blk, 0, stream>>>(QKV, Kp, Vp, ATTN);
  gemm_bt<true><<<dim3(2048 / 64, 2048 / 128), blk, 0, stream>>>(ATTN, WoT, outp, 2048, 2048, 2048);
}

// Round 11
// 262.733 us; speedup vs baseline: 1.3938x; 1.0113x over previous
//
#include <hip/hip_runtime.h>
#include <hip/hip_bf16.h>
#include <stdint.h>

#define S_LEN 2048
#define HDIM  2048
#define NHQ   16
#define NKVH  4
#define HD    128
#define WIN   1024
#define SM_SCALE 0.08838834764831845f
#define NEG_BIG  -1.0e30f

typedef __attribute__((ext_vector_type(8))) short short8;
typedef __attribute__((ext_vector_type(4))) float float4v;
typedef unsigned short u16;

static __device__ __forceinline__ float bf2f(u16 u) {
  union { unsigned int i; float f; } v; v.i = ((unsigned int)u) << 16; return v.f;
}
static __device__ __forceinline__ u16 f2bf(float f) {
  union { float f; unsigned int i; } v; v.f = f;
  unsigned int x = v.i;
  return (u16)((x + 0x7fffu + ((x >> 16) & 1u)) >> 16);   // RNE, finite inputs
}

// ---------------------------------------------------------------------------
// prep: one kernel for all input conditioning.
//  blocks [0,1024):        hs fp32 -> packed-A bf16 (8KB tiles [kc][m 128][8])
//  blocks [1024,7168):     Wq|Wk|Wv -> packed-B WqkvT (4KB tiles [kc][n 64][8])
//  blocks [7168,11264):    Wo -> packed-B WoT
// ---------------------------------------------------------------------------
__global__ __launch_bounds__(256) void prep(
    const float* __restrict__ hs, const float* __restrict__ Wq,
    const float* __restrict__ Wk, const float* __restrict__ Wv,
    const float* __restrict__ Wo, u16* __restrict__ hsB,
    u16* __restrict__ WqkvT, u16* __restrict__ WoT)
{
  const int b = blockIdx.x;
  if (b < 1024) {
    // ---- hs pack ----
    u16* dst = hsB + (size_t)b * 4096;
    const int mb = b >> 6, ks = b & 63;
#pragma unroll
    for (int i = 0; i < 2; ++i) {
      const int cid = i * 256 + threadIdx.x;
      const int kc  = cid & 3;
      const int m   = cid >> 2;
      const float* src = hs + ((size_t)(mb * 128 + m)) * 2048 + ks * 32 + kc * 8;
      const float4 v0 = *(const float4*)src;
      const float4 v1 = *(const float4*)(src + 4);
      short8 o;
      o[0] = (short)f2bf(v0.x); o[1] = (short)f2bf(v0.y);
      o[2] = (short)f2bf(v0.z); o[3] = (short)f2bf(v0.w);
      o[4] = (short)f2bf(v1.x); o[5] = (short)f2bf(v1.y);
      o[6] = (short)f2bf(v1.z); o[7] = (short)f2bf(v1.w);
      *(short8*)(dst + (kc * 128 + m) * 8) = o;
    }
    return;
  }

  // ---- weight transpose -> packed B ----
  __shared__ u16 t[32][33];
  const int tx = threadIdx.x & 31, ty = threadIdx.x >> 5;
  int n0, kstep;
  const float* W; u16* DT; int nsrc, N;
  if (b < 7168) {
    const int bb = b - 1024;            // 96 n-tiles x 64 k-tiles
    n0    = (bb % 96) * 32;
    kstep = bb / 96;
    if (n0 < 2048)      { W = Wq; nsrc = n0;        N = 2048; }
    else if (n0 < 2560) { W = Wk; nsrc = n0 - 2048; N = 512;  }
    else                { W = Wv; nsrc = n0 - 2560; N = 512;  }
    DT = WqkvT;
  } else {
    const int bb = b - 7168;            // 64 x 64
    n0    = (bb & 63) * 32;
    kstep = bb >> 6;
    W = Wo; nsrc = n0; N = 2048; DT = WoT;
  }
  const int k0 = kstep * 32;

#pragma unroll
  for (int i = 0; i < 4; ++i)
    t[ty + i * 8][tx] = f2bf(W[(size_t)(k0 + ty + i * 8) * N + nsrc + tx]);
  __syncthreads();
  const int kc = tx >> 3, e = tx & 7;
#pragma unroll
  for (int i = 0; i < 4; ++i) {
    const int n = n0 + ty + i * 8;
    DT[((size_t)((n >> 6) * 64 + kstep)) * 2048 + kc * 512 + (n & 63) * 8 + e]
        = t[tx][ty + i * 8];
  }
}

// ---------------------------------------------------------------------------
// GEMM on packed operands: C = A*B^T, bf16 in, fp32 accum. 128x64 tile,
// 4 waves of 64x32, conflict-free k-major LDS.
// EPI=0: fp32 row-major out (out-projection, writes d_out).
// EPI=1: fused QKV epilogue — in-register RoPE (q,k) via __shfl_xor pair
//        exchange, then route: q -> Qb row-major, k -> packed Kp, v -> Vp.
// ---------------------------------------------------------------------------
template <int EPI>
__global__ __launch_bounds__(256) void gemm_bt(
    const u16* __restrict__ Apk, const u16* __restrict__ Bpk,
    void* __restrict__ Cv, const float* __restrict__ fc,
    u16* __restrict__ Qb, u16* __restrict__ Kp, u16* __restrict__ Vp,
    int M, int N, int K)
{
  __shared__ u16 Als[4096];   // [kc 4][m 128][8]  8 KB
  __shared__ u16 Bls[2048];   // [kc 4][n 64][8]   4 KB

  const int tid  = threadIdx.x;
  const int lane = tid & 63;
  const int w    = tid >> 6;
  const int quad = lane >> 4;
  const int lc   = lane & 15;
  const int n0   = blockIdx.x * 64;
  const int m0   = blockIdx.y * 128;
  const int wr   = (w >> 1) * 64;
  const int wc   = (w & 1) * 32;
  const int ktiles = K >> 5;

  float4v acc[4][2];
#pragma unroll
  for (int i = 0; i < 4; ++i)
#pragma unroll
    for (int j = 0; j < 2; ++j) acc[i][j] = (float4v){0.f, 0.f, 0.f, 0.f};

  for (int ks = 0; ks < ktiles; ++ks) {
    const char* ab = (const char*)(Apk + ((size_t)((m0 >> 7) * ktiles + ks)) * 4096);
    const char* bb = (const char*)(Bpk + ((size_t)((n0 >> 6) * ktiles + ks)) * 2048);
    __syncthreads();
#pragma unroll
    for (int r = 0; r < 2; ++r) {
      const int off = r * 4096 + tid * 16;
      __builtin_amdgcn_global_load_lds(
          (__attribute__((address_space(1))) void*)(ab + off),
          (__attribute__((address_space(3))) void*)((char*)Als + off), 16, 0, 0);
    }
    {
      const int off = tid * 16;
      __builtin_amdgcn_global_load_lds(
          (__attribute__((address_space(1))) void*)(bb + off),
          (__attribute__((address_space(3))) void*)((char*)Bls + off), 16, 0, 0);
    }
    __syncthreads();

    short8 af[4], bfr[2];
#pragma unroll
    for (int mi = 0; mi < 4; ++mi)
      af[mi] = *(const short8*)(Als + quad * 1024 + (wr + mi * 16 + lc) * 8);
#pragma unroll
    for (int ni = 0; ni < 2; ++ni)
      bfr[ni] = *(const short8*)(Bls + quad * 512 + (wc + ni * 16 + lc) * 8);
#pragma unroll
    for (int mi = 0; mi < 4; ++mi)
#pragma unroll
      for (int ni = 0; ni < 2; ++ni)
        acc[mi][ni] = __builtin_amdgcn_mfma_f32_16x16x32_bf16(
            af[mi], bfr[ni], acc[mi][ni], 0, 0, 0);
  }

  if (EPI == 0) {
#pragma unroll
    for (int mi = 0; mi < 4; ++mi)
#pragma unroll
      for (int ni = 0; ni < 2; ++ni)
#pragma unroll
        for (int r = 0; r < 4; ++r) {
          const int row = m0 + wr + mi * 16 + quad * 4 + r;
          const int col = n0 + wc + ni * 16 + lc;
          ((float*)Cv)[(size_t)row * N + col] = acc[mi][ni][r];
        }
  } else {
    // ---- fused QKV epilogue: rope (q,k) + pack routing (block-uniform) ----
    if (n0 < 2560) {
      // q or k section: rope in-register, pairs live in adjacent lanes
#pragma unroll
      for (int mi = 0; mi < 4; ++mi)
#pragma unroll
        for (int ni = 0; ni < 2; ++ni)
#pragma unroll
          for (int r = 0; r < 4; ++r) {
            const int row = m0 + wr + mi * 16 + quad * 4 + r;
            const int col = n0 + wc + ni * 16 + lc;
            const int hh  = col & 127;                 // dim within head
            const float v = acc[mi][ni][r];
            const float p = __shfl_xor(v, 1);
            const float2 cs = *(const float2*)(fc + row * 128 + (hh & ~1));
            const float res = (col & 1) ? (p * cs.y + v * cs.x)
                                        : (v * cs.x - p * cs.y);
            if (n0 < 2048) {
              Qb[(size_t)row * 2048 + col] = f2bf(res);
            } else {
              const int kvh = (col - 2048) >> 7;
              const int kt  = row >> 6, key = row & 63;
              const int c   = hh >> 3, e = hh & 7;
              Kp[((size_t)(kvh * 32 + kt)) * 8192 + key * 128
                 + ((c ^ (key & 15)) * 8) + e] = f2bf(res);
            }
          }
    } else {
      // v section: transpose-pack
#pragma unroll
      for (int mi = 0; mi < 4; ++mi)
#pragma unroll
        for (int ni = 0; ni < 2; ++ni)
#pragma unroll
          for (int r = 0; r < 4; ++r) {
            const int row = m0 + wr + mi * 16 + quad * 4 + r;
            const int col = n0 + wc + ni * 16 + lc;
            const int kvh = (col - 2560) >> 7;
            const int hd  = col & 127;
            const int kt  = row >> 6, key = row & 63;
            const int c   = (key >> 3) ^ (hd & 7);
            Vp[((size_t)(kvh * 32 + kt)) * 8192 + hd * 64 + c * 8 + (key & 7)]
                = f2bf(acc[mi][ni][r]);
          }
    }
  }
}

// ---------------------------------------------------------------------------
// Flash attention (round-8 structure): per 64-key tile stage K + V^T via
// global_load_lds from packed Kp/Vp, ds_read_b128 fragments + MFMA; per-wave
// online softmax; epilogue writes ATTN in packed-A layout. grid = (S/64, NH).
// ---------------------------------------------------------------------------
__global__ __launch_bounds__(256) void attn_kernel(
    const u16* __restrict__ Qb, const u16* __restrict__ kp,
    const u16* __restrict__ vp, u16* __restrict__ out)
{
  __shared__ u16 Kls[64 * 128];
  __shared__ u16 Vls[128 * 64];
  __shared__ u16 P[4 * 16 * 72];

  const int tid  = threadIdx.x;
  const int lane = tid & 63;
  const int w    = tid >> 6;
  const int quad = lane >> 4;
  const int lc   = lane & 15;
  const int q0   = blockIdx.x * 64;
  const int h    = blockIdx.y;
  const int kvh  = h >> 2;
  const int rb   = q0 + w * 16;

  short8 qf[4];
  {
    const u16* qp = Qb + (size_t)(rb + lc) * 2048 + h * HD + quad * 8;
#pragma unroll
    for (int ks = 0; ks < 4; ++ks) qf[ks] = *(const short8*)(qp + ks * 32);
  }

  float4v o[8];
#pragma unroll
  for (int i = 0; i < 8; ++i) o[i] = (float4v){0.f, 0.f, 0.f, 0.f};
  float mrow[4], lrow[4];
#pragma unroll
  for (int r = 0; r < 4; ++r) { mrow[r] = NEG_BIG; lrow[r] = 0.f; }

  int jmin_blk = q0 - (WIN - 1); if (jmin_blk < 0) jmin_blk = 0;
  const int kt_begin = jmin_blk >> 6;
  const int kt_end   = q0 >> 6;

  const size_t tbase = (size_t)(kvh * 32) * 8192;

  for (int kt = kt_begin; kt <= kt_end; ++kt) {
    const int k0 = kt * 64;

    __syncthreads();
    {
      const u16* kg = kp + tbase + (size_t)kt * 8192;
      const u16* vg = vp + tbase + (size_t)kt * 8192;
#pragma unroll
      for (int i = 0; i < 4; ++i) {
        const int off = i * 4096 + tid * 16;
        __builtin_amdgcn_global_load_lds(
            (__attribute__((address_space(1))) void*)((const char*)kg + off),
            (__attribute__((address_space(3))) void*)((char*)Kls + off), 16, 0, 0);
        __builtin_amdgcn_global_load_lds(
            (__attribute__((address_space(1))) void*)((const char*)vg + off),
            (__attribute__((address_space(3))) void*)((char*)Vls + off), 16, 0, 0);
      }
    }
    __syncthreads();

    if (k0 > rb + 15 || k0 + 63 < rb - (WIN - 1)) continue;

    float4v sacc[4];
#pragma unroll
    for (int i = 0; i < 4; ++i) sacc[i] = (float4v){0.f, 0.f, 0.f, 0.f};
#pragma unroll
    for (int ks = 0; ks < 4; ++ks) {
#pragma unroll
      for (int nt = 0; nt < 4; ++nt) {
        const int key = nt * 16 + lc;
        const int c   = (ks * 4 + quad) ^ (key & 15);
        short8 kb = *(const short8*)(Kls + key * 128 + c * 8);
        sacc[nt] = __builtin_amdgcn_mfma_f32_16x16x32_bf16(qf[ks], kb, sacc[nt], 0, 0, 0);
      }
    }

    const bool full = (k0 + 63 <= rb) && ((rb + 15 - k0) <= WIN - 1);
    float sv[4][4];
    bool  ok[4][4];
    float rmax[4] = {NEG_BIG, NEG_BIG, NEG_BIG, NEG_BIG};
#pragma unroll
    for (int nt = 0; nt < 4; ++nt) {
      const int j = k0 + nt * 16 + lc;
#pragma unroll
      for (int r = 0; r < 4; ++r) {
        const int i = rb + quad * 4 + r;
        const bool valid = full || ((j <= i) && (i - j < WIN));
        float s = sacc[nt][r] * SM_SCALE;
        s = valid ? s : NEG_BIG;
        sv[nt][r] = s;
        ok[nt][r] = valid;
        rmax[r] = fmaxf(rmax[r], s);
      }
    }
#pragma unroll
    for (int off = 1; off < 16; off <<= 1)
#pragma unroll
      for (int r = 0; r < 4; ++r)
        rmax[r] = fmaxf(rmax[r], __shfl_xor(rmax[r], off, 64));

    float alpha[4], rsum[4];
#pragma unroll
    for (int r = 0; r < 4; ++r) {
      const float mn = fmaxf(mrow[r], rmax[r]);
      alpha[r] = __expf(mrow[r] - mn);
      mrow[r] = mn;
      rsum[r] = 0.f;
    }
#pragma unroll
    for (int nt = 0; nt < 4; ++nt)
#pragma unroll
      for (int r = 0; r < 4; ++r) {
        const float p = ok[nt][r] ? __expf(sv[nt][r] - mrow[r]) : 0.f;
        rsum[r] += p;
        P[(w * 16 + quad * 4 + r) * 72 + nt * 16 + lc] = f2bf(p);
      }
#pragma unroll
    for (int off = 1; off < 16; off <<= 1)
#pragma unroll
      for (int r = 0; r < 4; ++r)
        rsum[r] += __shfl_xor(rsum[r], off, 64);
#pragma unroll
    for (int r = 0; r < 4; ++r) lrow[r] = lrow[r] * alpha[r] + rsum[r];
#pragma unroll
    for (int i = 0; i < 8; ++i)
#pragma unroll
      for (int r = 0; r < 4; ++r) o[i][r] *= alpha[r];

#pragma unroll
    for (int ktk = 0; ktk < 2; ++ktk) {
      short8 pa = *(const short8*)(P + (w * 16 + lc) * 72 + ktk * 32 + quad * 8);
#pragma unroll
      for (int nt2 = 0; nt2 < 8; ++nt2) {
        const int hd = nt2 * 16 + lc;
        const int c  = (ktk * 4 + quad) ^ (hd & 7);
        short8 vb = *(const short8*)(Vls + hd * 64 + c * 8);
        o[nt2] = __builtin_amdgcn_mfma_f32_16x16x32_bf16(pa, vb, o[nt2], 0, 0, 0);
      }
    }
  }

  // epilogue: ATTN in packed-A layout [mblk][kstep][kc][m][8]
#pragma unroll
  for (int r = 0; r < 4; ++r) {
    const float inv = (lrow[r] > 0.f) ? (1.f / lrow[r]) : 0.f;
    const int row = rb + quad * 4 + r;
    const size_t mbase = (size_t)(row >> 7) * 64;
    const int m = row & 127;
#pragma unroll
    for (int nt2 = 0; nt2 < 8; ++nt2) {
      const int col = h * HD + nt2 * 16 + lc;
      const int kstep = col >> 5, kc = (col >> 3) & 3, e = col & 7;
      out[(mbase + kstep) * 4096 + kc * 1024 + m * 8 + e] = f2bf(o[nt2][r] * inv);
    }
  }
}

// ---------------------------------------------------------------------------
extern "C" void kernel_launch(void* const* d_in, const int* in_sizes, int n_in,
                              void* d_out, int out_size, void* d_ws, size_t ws_size,
                              hipStream_t stream) {
  const float* hs = (const float*)d_in[0];   // fp32
  const float* fc = (const float*)d_in[1];   // fp32
  // d_in[2] attention_mask all-true; d_in[3] causal analytic; d_in[4] arange
  const float* Wq = (const float*)d_in[5];
  const float* Wk = (const float*)d_in[6];
  const float* Wv = (const float*)d_in[7];
  const float* Wo = (const float*)d_in[8];
  float* outp = (float*)d_out;               // fp32 output

  u16* hsB   = (u16*)d_ws;                           // packed A, 2048x2048
  u16* WqkvT = hsB   + (size_t)2048 * 2048;          // packed B, 3072x2048
  u16* WoT   = WqkvT + (size_t)3072 * 2048;          // packed B, 2048x2048
  u16* Qb    = WoT   + (size_t)2048 * 2048;          // row-major 2048x2048
  u16* ATTN  = Qb    + (size_t)2048 * 2048;          // packed A, 2048x2048
  u16* Kp    = ATTN  + (size_t)2048 * 2048;          // 4 x 32 x 64 x 128
  u16* Vp    = Kp    + (size_t)4 * 2048 * 128;       // 4 x 32 x 128 x 64

  dim3 blk(256);
  prep<<<dim3(11264), blk, 0, stream>>>(hs, Wq, Wk, Wv, Wo, hsB, WqkvT, WoT);
  gemm_bt<1><<<dim3(3072 / 64, 2048 / 128), blk, 0, stream>>>(
      hsB, WqkvT, nullptr, fc, Qb, Kp, Vp, 2048, 3072, 2048);
  attn_kernel<<<dim3(2048 / 64, NHQ), blk, 0, stream>>>(Qb, Kp, Vp, ATTN);
  gemm_bt<0><<<dim3(2048 / 64, 2048 / 128), blk, 0, stream>>>(
      ATTN, WoT, outp, nullptr, nullptr, nullptr, nullptr, 2048, 2048, 2048);
}